// Round 5
// baseline (302.000 us; speedup 1.0000x reference)
//
#include <hip/hip_runtime.h>

// Problem sizes (fixed by the reference)
#define NN 512   // graph nodes
#define DD 768   // feature dim (= output dim)
#define BB 32    // batch
#define KK 3072  // final GEMM K (4 slabs x 768)
#define NTK 96   // K-tiles of 32

typedef __bf16 bf16;
typedef bf16 bf16x8 __attribute__((ext_vector_type(8)));
typedef bf16 bf16x4 __attribute__((ext_vector_type(4)));
typedef float f32x4 __attribute__((ext_vector_type(4)));

typedef const unsigned int __attribute__((address_space(1)))* gas_cuintp;
typedef unsigned int __attribute__((address_space(3)))* las_uintp;

__device__ __forceinline__ void async_copy16(const void* g, void* l) {
    __builtin_amdgcn_global_load_lds((gas_cuintp)g, (las_uintp)l, 16, 0, 0);
}

// ---------------------------------------------------------------------------
// Prep kernels
// ---------------------------------------------------------------------------

__global__ void k_rowsum(const float* __restrict__ adj, float* __restrict__ dv) {
    const int i = blockIdx.x;
    const int lane = threadIdx.x;  // 64
    float s = 0.f;
#pragma unroll
    for (int j = 0; j < NN / 64; ++j) s += adj[(size_t)i * NN + lane + j * 64];
#pragma unroll
    for (int off = 32; off; off >>= 1) s += __shfl_down(s, off);
    if (lane == 0) dv[i] = rsqrtf(s + 1.0f);
}

// support[n,k] = (adj[k,n] + (n==k)) * dv[n] * dv[k]; writes Sb[n][k] and SbT[k][n]
__global__ void k_support2(const float* __restrict__ adj, const float* __restrict__ dv,
                           bf16* __restrict__ sb, bf16* __restrict__ sbt) {
    __shared__ bf16 tile[32][33];
    const int k0 = blockIdx.y * 32;
    const int n0 = blockIdx.x * 32;
    const int x = threadIdx.x;
    const int y = threadIdx.y;
    const float dn = dv[n0 + x];
#pragma unroll
    for (int q = 0; q < 4; ++q) {
        const int k = k0 + y + q * 8;
        float m = adj[(size_t)k * NN + n0 + x] + ((k == n0 + x) ? 1.0f : 0.0f);
        bf16 v = (bf16)(m * dn * dv[k]);
        sbt[(size_t)k * NN + n0 + x] = v;
        tile[y + q * 8][x] = v;
    }
    __syncthreads();
#pragma unroll
    for (int q = 0; q < 4; ++q)
        sb[(size_t)(n0 + y + q * 8) * NN + k0 + x] = tile[x][y + q * 8];
}

// WtK[o][m*768 + d] = w[d*4+m][o]   (K-contiguous B for the final GEMM)
__global__ void k_prepwt2(const float* __restrict__ w, bf16* __restrict__ wt) {
    __shared__ bf16 tile[32][33];
    const int m = blockIdx.z;
    const int d0 = blockIdx.y * 32;
    const int o0 = blockIdx.x * 32;
    const int x = threadIdx.x, y = threadIdx.y;
#pragma unroll
    for (int q = 0; q < 4; ++q) {
        const int d = d0 + y + q * 8;
        tile[y + q * 8][x] = (bf16)w[(size_t)(d * 4 + m) * DD + o0 + x];
    }
    __syncthreads();
#pragma unroll
    for (int q = 0; q < 4; ++q)
        wt[(size_t)(o0 + y + q * 8) * KK + m * DD + d0 + x] = tile[x][y + q * 8];
}

// fused: f32 [b][n][d] -> Xr4 slab0 (bf16, [b*n][s=0 .. 768)) AND XT0 bf16 [b][d][n]
__global__ __launch_bounds__(256) void k_prepx(const float* __restrict__ in,
                                               bf16* __restrict__ xr4,
                                               bf16* __restrict__ xt) {
    __shared__ bf16 tile[64][65];
    const int b = blockIdx.z;
    const int d0 = blockIdx.x * 64;
    const int n0 = blockIdx.y * 64;
    const int t = threadIdx.x;
    const int tx = t & 15;
    const int ty = t >> 4;
    const float* ib = in + (size_t)b * NN * DD;
#pragma unroll
    for (int q = 0; q < 4; ++q) {
        const int n = n0 + ty + q * 16;
        f32x4 v = *(const f32x4*)&ib[(size_t)n * DD + d0 + tx * 4];
        bf16x4 p;
#pragma unroll
        for (int j = 0; j < 4; ++j) p[j] = (bf16)v[j];
        *(bf16x4*)&xr4[(size_t)(b * NN + n) * KK + d0 + tx * 4] = p;
#pragma unroll
        for (int j = 0; j < 4; ++j) tile[ty + q * 16][tx * 4 + j] = p[j];
    }
    __syncthreads();
    bf16* xtb = xt + (size_t)b * DD * NN;
#pragma unroll
    for (int q = 0; q < 4; ++q) {
        const int d = ty + q * 16;
        bf16x4 p;
#pragma unroll
        for (int j = 0; j < 4; ++j) p[j] = tile[tx * 4 + j][d];
        *(bf16x4*)&xtb[(size_t)(d0 + d) * NN + n0 + tx * 4] = p;
    }
}

// ---------------------------------------------------------------------------
// Shared 128x128 bt-form MFMA tile loop (m97-style, used by poly/apply)
// ---------------------------------------------------------------------------
__device__ __forceinline__ void mfma_tile_loop(const bf16* __restrict__ A,
                                               const bf16* __restrict__ B,
                                               int lda, int ldb, int K,
                                               int i0, int j0,
                                               bf16* At, bf16* Bt, f32x4 acc[4][4]) {
    const int t = threadIdx.x;
    const int lane = t & 63;
    const int w = t >> 6;
    const int wr = w >> 1, wc = w & 1;
    const int srow = t >> 2;
    const int scol = (t & 3) * 8;
    const int fr = lane & 15;
    const int fk = (lane >> 4) * 8;
    for (int k0 = 0; k0 < K; k0 += 32) {
        __syncthreads();
        async_copy16(A + (size_t)(i0 + srow) * lda + k0 + scol, &At[t * 8]);
        async_copy16(A + (size_t)(i0 + 64 + srow) * lda + k0 + scol, &At[2048 + t * 8]);
        async_copy16(B + (size_t)(j0 + srow) * ldb + k0 + scol, &Bt[t * 8]);
        async_copy16(B + (size_t)(j0 + 64 + srow) * ldb + k0 + scol, &Bt[2048 + t * 8]);
        __syncthreads();
        bf16x8 af[4], bg[4];
#pragma unroll
        for (int mi = 0; mi < 4; ++mi)
            af[mi] = *(const bf16x8*)&At[(wr * 64 + mi * 16 + fr) * 32 + fk];
#pragma unroll
        for (int ni = 0; ni < 4; ++ni)
            bg[ni] = *(const bf16x8*)&Bt[(wc * 64 + ni * 16 + fr) * 32 + fk];
#pragma unroll
        for (int mi = 0; mi < 4; ++mi)
#pragma unroll
            for (int ni = 0; ni < 4; ++ni)
                acc[mi][ni] = __builtin_amdgcn_mfma_f32_16x16x32_bf16(
                    af[mi], bg[ni], acc[mi][ni], 0, 0, 0);
    }
}

// P2 = 2*S@S - I  (and P2T)
__global__ __launch_bounds__(256) void k_poly2(const bf16* __restrict__ Sb,
                                               const bf16* __restrict__ SbT,
                                               bf16* __restrict__ P2,
                                               bf16* __restrict__ P2T) {
    __shared__ bf16 At[4096] __attribute__((aligned(16)));
    __shared__ bf16 Bt[4096] __attribute__((aligned(16)));
    const int i0 = blockIdx.y * 128, j0 = blockIdx.x * 128;
    f32x4 acc[4][4];
#pragma unroll
    for (int mi = 0; mi < 4; ++mi)
#pragma unroll
        for (int ni = 0; ni < 4; ++ni) acc[mi][ni] = f32x4{0.f, 0.f, 0.f, 0.f};
    mfma_tile_loop(Sb, SbT, NN, NN, NN, i0, j0, At, Bt, acc);
    const int t = threadIdx.x, lane = t & 63, w = t >> 6;
    const int wr = w >> 1, wc = w & 1;
    const int fr = lane & 15, rb = (lane >> 4) * 4;
#pragma unroll
    for (int mi = 0; mi < 4; ++mi)
#pragma unroll
        for (int ni = 0; ni < 4; ++ni) {
            const int ii = i0 + wr * 64 + mi * 16 + rb;
            const int jj = j0 + wc * 64 + ni * 16 + fr;
#pragma unroll
            for (int tt = 0; tt < 4; ++tt) {
                float v = 2.f * acc[mi][ni][tt] - ((ii + tt) == jj ? 1.f : 0.f);
                bf16 bv = (bf16)v;
                P2[(size_t)(ii + tt) * NN + jj] = bv;
                P2T[(size_t)jj * NN + (ii + tt)] = bv;
            }
        }
}

// P3 = 2*S@P2 - S
__global__ __launch_bounds__(256) void k_poly3(const bf16* __restrict__ Sb,
                                               const bf16* __restrict__ P2T,
                                               bf16* __restrict__ P3) {
    __shared__ bf16 At[4096] __attribute__((aligned(16)));
    __shared__ bf16 Bt[4096] __attribute__((aligned(16)));
    const int i0 = blockIdx.y * 128, j0 = blockIdx.x * 128;
    f32x4 acc[4][4];
#pragma unroll
    for (int mi = 0; mi < 4; ++mi)
#pragma unroll
        for (int ni = 0; ni < 4; ++ni) acc[mi][ni] = f32x4{0.f, 0.f, 0.f, 0.f};
    mfma_tile_loop(Sb, P2T, NN, NN, NN, i0, j0, At, Bt, acc);
    const int t = threadIdx.x, lane = t & 63, w = t >> 6;
    const int wr = w >> 1, wc = w & 1;
    const int fr = lane & 15, rb = (lane >> 4) * 4;
#pragma unroll
    for (int mi = 0; mi < 4; ++mi)
#pragma unroll
        for (int ni = 0; ni < 4; ++ni) {
            const int ii = i0 + wr * 64 + mi * 16 + rb;
            const int jj = j0 + wc * 64 + ni * 16 + fr;
#pragma unroll
            for (int tt = 0; tt < 4; ++tt) {
                float v = 2.f * acc[mi][ni][tt] - (float)Sb[(size_t)(ii + tt) * NN + jj];
                P3[(size_t)(ii + tt) * NN + jj] = (bf16)v;
            }
        }
}

// Xr4[b*n][(m+1)*768 + d] = sum_k P_m[n][k] * XT0[b][d][k];  P_m at P + 2*m*NN*NN
__global__ __launch_bounds__(256) void k_apply(const bf16* __restrict__ P,
                                               const bf16* __restrict__ XT0,
                                               bf16* __restrict__ Xr4) {
    __shared__ bf16 At[4096] __attribute__((aligned(16)));
    __shared__ bf16 Bt[4096] __attribute__((aligned(16)));
    __shared__ bf16 epi[32 * 136] __attribute__((aligned(16)));
    const int z = blockIdx.z;
    const int m = z >> 5;
    const int b = z & 31;
    const int i0 = blockIdx.y * 128;  // n
    const int j0 = blockIdx.x * 128;  // d
    const bf16* A = P + (size_t)(2 * m) * NN * NN;  // Sb -> P2 -> P3 (stride 2 slots)
    const bf16* B = XT0 + (size_t)b * DD * NN;
    f32x4 acc[4][4];
#pragma unroll
    for (int mi = 0; mi < 4; ++mi)
#pragma unroll
        for (int ni = 0; ni < 4; ++ni) acc[mi][ni] = f32x4{0.f, 0.f, 0.f, 0.f};
    mfma_tile_loop(A, B, NN, NN, NN, i0, j0, At, Bt, acc);

    bf16* ob = Xr4 + (size_t)b * NN * KK + (m + 1) * DD;  // row-stride KK
    const int t = threadIdx.x, lane = t & 63, w = t >> 6;
    const int wr = w >> 1, wc = w & 1;
    const int fr = lane & 15, rb = (lane >> 4) * 4;
#pragma unroll
    for (int mi = 0; mi < 4; ++mi) {
        __syncthreads();
#pragma unroll
        for (int ni = 0; ni < 4; ++ni) {
            const int col = wc * 64 + ni * 16 + fr;
#pragma unroll
            for (int tt = 0; tt < 4; ++tt) {
                const int lr = wr * 16 + rb + tt;
                epi[lr * 136 + col] = (bf16)acc[mi][ni][tt];
            }
        }
        __syncthreads();
#pragma unroll
        for (int it = 0; it < 2; ++it) {
            const int idx = t + it * 256;
            const int lr = idx >> 4;
            const int cq = idx & 15;
            bf16x8 vv = *(const bf16x8*)&epi[lr * 136 + cq * 8];
            const int gr = i0 + (lr >> 4) * 64 + mi * 16 + (lr & 15);
            *(bf16x8*)&ob[(size_t)gr * KK + j0 + cq * 8] = vv;
        }
    }
}

// ---------------------------------------------------------------------------
// Final GEMM, 256x256 tile / BK=32 / 8 waves / double-buffer / counted vmcnt.
// A = Xr4 [16384][3072], B = WtK [768][3072] (bt-form), C = out [16384][768].
// LDS read-side swizzle via pre-swizzled global source (linear gload_lds dest).
// ---------------------------------------------------------------------------
__device__ __forceinline__ void stage_tile(const bf16* __restrict__ p, int rowbase,
                                           int kt, bf16* ldsdst, int t) {
    const int srow = t >> 2;
    const int sg = (t & 3) ^ ((t >> 2) & 3) ^ ((t >> 4) & 3);  // source granule swizzle
    const bf16* s0 = p + (size_t)(rowbase + srow) * KK + kt * 32 + sg * 8;
    const bf16* s1 = s0 + (size_t)128 * KK;
    async_copy16(s0, ldsdst + t * 8);          // rows 0..127 of the tile
    async_copy16(s1, ldsdst + 4096 + t * 8);   // rows 128..255
}

__global__ __launch_bounds__(512, 2)
void k_final512(const bf16* __restrict__ A, const bf16* __restrict__ Bw,
                const float* __restrict__ bias, float* __restrict__ out) {
    __shared__ bf16 lds[2][2][256 * 32] __attribute__((aligned(16)));  // 64 KiB
    const int t = threadIdx.x;
    const int lane = t & 63;
    const int w = t >> 6;       // 0..7
    const int wr = w >> 2;      // 0..1  (row half)
    const int wc = w & 3;       // 0..3  (col quarter)
    const int wgid = blockIdx.x;                    // 0..191
    const int swz = (wgid & 7) * 24 + (wgid >> 3);  // bijective XCD swizzle
    const int i0 = (swz / 3) * 256;                 // bn rows
    const int j0 = (swz % 3) * 256;                 // o cols
    const int fr = lane & 15;
    const int g = lane >> 4;    // k-granule 0..3
    const int rslot8 = (g ^ (fr & 3) ^ ((fr >> 2) & 3)) * 8;  // read-side swizzle
    const int abase = (wr * 128 + fr) * 32 + rslot8;
    const int bbase = (wc * 64 + fr) * 32 + rslot8;

    f32x4 acc[8][4];
#pragma unroll
    for (int mi = 0; mi < 8; ++mi)
#pragma unroll
        for (int ni = 0; ni < 4; ++ni) acc[mi][ni] = f32x4{0.f, 0.f, 0.f, 0.f};

    // Prologue: A(0)->buf0.A, B(0)->buf0.B, B(1)->buf1.B; allow B(1) in flight.
    stage_tile(A, i0, 0, &lds[0][0][0], t);
    stage_tile(Bw, j0, 0, &lds[0][1][0], t);
    stage_tile(Bw, j0, 1, &lds[1][1][0], t);
    asm volatile("s_waitcnt vmcnt(2)" ::: "memory");
    __builtin_amdgcn_s_barrier();
    __builtin_amdgcn_sched_barrier(0);

    for (int kt = 0; kt < NTK; ++kt) {
        const int cur = kt & 1;
        const bf16* As = &lds[cur][0][0];
        const bf16* Bs = &lds[cur][1][0];
        // ---- phase 0: B-frags + A-frags(mi 0..3); prefetch A(kt+1) -> other buf
        bf16x8 bg[4], af[4];
#pragma unroll
        for (int ni = 0; ni < 4; ++ni) bg[ni] = *(const bf16x8*)&Bs[bbase + ni * 512];
#pragma unroll
        for (int mi = 0; mi < 4; ++mi) af[mi] = *(const bf16x8*)&As[abase + mi * 512];
        if (kt + 1 < NTK) stage_tile(A, i0, kt + 1, &lds[cur ^ 1][0][0], t);
        __builtin_amdgcn_s_barrier();
        __builtin_amdgcn_sched_barrier(0);
        __builtin_amdgcn_s_setprio(1);
#pragma unroll
        for (int mi = 0; mi < 4; ++mi)
#pragma unroll
            for (int ni = 0; ni < 4; ++ni)
                acc[mi][ni] = __builtin_amdgcn_mfma_f32_16x16x32_bf16(
                    af[mi], bg[ni], acc[mi][ni], 0, 0, 0);
        __builtin_amdgcn_s_setprio(0);
        __builtin_amdgcn_s_barrier();
        __builtin_amdgcn_sched_barrier(0);
        // ---- phase 1: A-frags(mi 4..7); prefetch B(kt+2) -> current buf's dead B
#pragma unroll
        for (int mi = 0; mi < 4; ++mi)
            af[mi] = *(const bf16x8*)&As[abase + 2048 + mi * 512];
        if (kt + 2 < NTK) stage_tile(Bw, j0, kt + 2, &lds[cur][1][0], t);
        __builtin_amdgcn_s_barrier();
        __builtin_amdgcn_sched_barrier(0);
        __builtin_amdgcn_s_setprio(1);
#pragma unroll
        for (int mi = 0; mi < 4; ++mi)
#pragma unroll
            for (int ni = 0; ni < 4; ++ni)
                acc[4 + mi][ni] = __builtin_amdgcn_mfma_f32_16x16x32_bf16(
                    af[mi], bg[ni], acc[4 + mi][ni], 0, 0, 0);
        __builtin_amdgcn_s_setprio(0);
        // ---- tile boundary: counted wait (next-next B may stay in flight)
        if (kt < NTK - 2) {
            asm volatile("s_waitcnt vmcnt(2)" ::: "memory");
        } else {
            asm volatile("s_waitcnt vmcnt(0)" ::: "memory");
        }
        __builtin_amdgcn_s_barrier();
        __builtin_amdgcn_sched_barrier(0);
    }

    // Epilogue: direct f32 stores (same fragment convention as verified kernels)
    const int rb = g * 4;
#pragma unroll
    for (int ni = 0; ni < 4; ++ni) {
        const int jj = j0 + wc * 64 + ni * 16 + fr;
        const float bv = bias[jj];
#pragma unroll
        for (int mi = 0; mi < 8; ++mi) {
            const int ii = i0 + wr * 128 + mi * 16 + rb;
#pragma unroll
            for (int tt = 0; tt < 4; ++tt)
                out[(size_t)(ii + tt) * DD + jj] = acc[mi][ni][tt] + bv;
        }
    }
}

// ---------------------------------------------------------------------------
// Launch
// ---------------------------------------------------------------------------
extern "C" void kernel_launch(void* const* d_in, const int* in_sizes, int n_in,
                              void* d_out, int out_size, void* d_ws, size_t ws_size,
                              hipStream_t stream) {
    const float* inputs = (const float*)d_in[0];   // [32,512,768]
    const float* adj = (const float*)d_in[1];      // [512,512]
    const float* weights = (const float*)d_in[2];  // [3072,768]
    const float* biases = (const float*)d_in[3];   // [768]
    float* out = (float*)d_out;                    // [32,512,768]

    char* ws = (char*)d_ws;
    const size_t SQ = (size_t)NN * NN * 2;  // 512 KiB per P-slot
    float* dv = (float*)(ws + 0);
    // P-slot layout (stride SQ): [Sb][SbT][P2][P2T][P3] -> Sb,P2,P3 at even slots
    bf16* Sb = (bf16*)(ws + 4096);
    bf16* SbT = (bf16*)(ws + 4096 + SQ);
    bf16* P2 = (bf16*)(ws + 4096 + 2 * SQ);
    bf16* P2T = (bf16*)(ws + 4096 + 3 * SQ);
    bf16* P3 = (bf16*)(ws + 4096 + 4 * SQ);
    bf16* WtK = (bf16*)(ws + 4096 + 5 * SQ);             // 768*3072*2 = 4.5 MiB
    char* p = ws + 4096 + 5 * SQ + (size_t)DD * KK * 2;
    bf16* XT0 = (bf16*)p;                                // 24 MiB
    bf16* Xr4 = (bf16*)(p + (size_t)BB * NN * DD * 2);   // [16384][3072] = 96 MiB
    // total ~127.5 MiB

    k_rowsum<<<NN, 64, 0, stream>>>(adj, dv);
    k_support2<<<dim3(16, 16), dim3(32, 8), 0, stream>>>(adj, dv, Sb, SbT);
    k_prepwt2<<<dim3(24, 24, 4), dim3(32, 8), 0, stream>>>(weights, WtK);
    k_prepx<<<dim3(DD / 64, NN / 64, BB), 256, 0, stream>>>(inputs, Xr4, XT0);

    k_poly2<<<dim3(4, 4), 256, 0, stream>>>(Sb, SbT, P2, P2T);
    k_poly3<<<dim3(4, 4), 256, 0, stream>>>(Sb, P2T, P3);

    k_apply<<<dim3(DD / 128, NN / 128, 3 * BB), 256, 0, stream>>>(Sb, XT0, Xr4);

    k_final512<<<192, 512, 0, stream>>>(Xr4, WtK, biases, out);
}

// Round 6
// 283.848 us; speedup vs baseline: 1.0639x; 1.0639x over previous
//
#include <hip/hip_runtime.h>

// Problem sizes (fixed by the reference)
#define NN 512   // graph nodes
#define DD 768   // feature dim (= output dim)
#define BB 32    // batch
#define KK 3072  // final GEMM K (4 slabs x 768)

typedef __bf16 bf16;
typedef bf16 bf16x8 __attribute__((ext_vector_type(8)));
typedef bf16 bf16x4 __attribute__((ext_vector_type(4)));
typedef float f32x4 __attribute__((ext_vector_type(4)));

typedef const unsigned int __attribute__((address_space(1)))* gas_cuintp;
typedef unsigned int __attribute__((address_space(3)))* las_uintp;

__device__ __forceinline__ void async_copy16(const void* g, void* l) {
    __builtin_amdgcn_global_load_lds((gas_cuintp)g, (las_uintp)l, 16, 0, 0);
}

// ---------------------------------------------------------------------------
// Prep kernels (verified in rounds 1-5, unchanged except pointer wiring)
// ---------------------------------------------------------------------------

__global__ void k_rowsum(const float* __restrict__ adj, float* __restrict__ dv) {
    const int i = blockIdx.x;
    const int lane = threadIdx.x;  // 64
    float s = 0.f;
#pragma unroll
    for (int j = 0; j < NN / 64; ++j) s += adj[(size_t)i * NN + lane + j * 64];
#pragma unroll
    for (int off = 32; off; off >>= 1) s += __shfl_down(s, off);
    if (lane == 0) dv[i] = rsqrtf(s + 1.0f);
}

// support[n,k] = (adj[k,n] + (n==k)) * dv[n] * dv[k]; writes Sb[n][k] and SbT[k][n]
__global__ void k_support2(const float* __restrict__ adj, const float* __restrict__ dv,
                           bf16* __restrict__ sb, bf16* __restrict__ sbt) {
    __shared__ bf16 tile[32][33];
    const int k0 = blockIdx.y * 32;
    const int n0 = blockIdx.x * 32;
    const int x = threadIdx.x;
    const int y = threadIdx.y;
    const float dn = dv[n0 + x];
#pragma unroll
    for (int q = 0; q < 4; ++q) {
        const int k = k0 + y + q * 8;
        float m = adj[(size_t)k * NN + n0 + x] + ((k == n0 + x) ? 1.0f : 0.0f);
        bf16 v = (bf16)(m * dn * dv[k]);
        sbt[(size_t)k * NN + n0 + x] = v;
        tile[y + q * 8][x] = v;
    }
    __syncthreads();
#pragma unroll
    for (int q = 0; q < 4; ++q)
        sb[(size_t)(n0 + y + q * 8) * NN + k0 + x] = tile[x][y + q * 8];
}

// WtK[o][m*768 + d] = w[d*4+m][o]   (K-contiguous B for the final GEMM)
__global__ void k_prepwt2(const float* __restrict__ w, bf16* __restrict__ wt) {
    __shared__ bf16 tile[32][33];
    const int m = blockIdx.z;
    const int d0 = blockIdx.y * 32;
    const int o0 = blockIdx.x * 32;
    const int x = threadIdx.x, y = threadIdx.y;
#pragma unroll
    for (int q = 0; q < 4; ++q) {
        const int d = d0 + y + q * 8;
        tile[y + q * 8][x] = (bf16)w[(size_t)(d * 4 + m) * DD + o0 + x];
    }
    __syncthreads();
#pragma unroll
    for (int q = 0; q < 4; ++q)
        wt[(size_t)(o0 + y + q * 8) * KK + m * DD + d0 + x] = tile[x][y + q * 8];
}

// fused: f32 [b][n][d] -> Xr4 slab0 (bf16, [b*n][0..768)) AND XT0 bf16 [b][d][n]
__global__ __launch_bounds__(256) void k_prepx(const float* __restrict__ in,
                                               bf16* __restrict__ xr4,
                                               bf16* __restrict__ xt) {
    __shared__ bf16 tile[64][65];
    const int b = blockIdx.z;
    const int d0 = blockIdx.x * 64;
    const int n0 = blockIdx.y * 64;
    const int t = threadIdx.x;
    const int tx = t & 15;
    const int ty = t >> 4;
    const float* ib = in + (size_t)b * NN * DD;
#pragma unroll
    for (int q = 0; q < 4; ++q) {
        const int n = n0 + ty + q * 16;
        f32x4 v = *(const f32x4*)&ib[(size_t)n * DD + d0 + tx * 4];
        bf16x4 p;
#pragma unroll
        for (int j = 0; j < 4; ++j) p[j] = (bf16)v[j];
        *(bf16x4*)&xr4[(size_t)(b * NN + n) * KK + d0 + tx * 4] = p;
#pragma unroll
        for (int j = 0; j < 4; ++j) tile[ty + q * 16][tx * 4 + j] = p[j];
    }
    __syncthreads();
    bf16* xtb = xt + (size_t)b * DD * NN;
#pragma unroll
    for (int q = 0; q < 4; ++q) {
        const int d = ty + q * 16;
        bf16x4 p;
#pragma unroll
        for (int j = 0; j < 4; ++j) p[j] = tile[tx * 4 + j][d];
        *(bf16x4*)&xtb[(size_t)(d0 + d) * NN + n0 + tx * 4] = p;
    }
}

// ---------------------------------------------------------------------------
// Shared 128x128 bt-form MFMA tile loop (m97-style, used by poly2/poly3)
// ---------------------------------------------------------------------------
__device__ __forceinline__ void mfma_tile_loop(const bf16* __restrict__ A,
                                               const bf16* __restrict__ B,
                                               int lda, int ldb, int K,
                                               int i0, int j0,
                                               bf16* At, bf16* Bt, f32x4 acc[4][4]) {
    const int t = threadIdx.x;
    const int lane = t & 63;
    const int w = t >> 6;
    const int wr = w >> 1, wc = w & 1;
    const int srow = t >> 2;
    const int scol = (t & 3) * 8;
    const int fr = lane & 15;
    const int fk = (lane >> 4) * 8;
    for (int k0 = 0; k0 < K; k0 += 32) {
        __syncthreads();
        async_copy16(A + (size_t)(i0 + srow) * lda + k0 + scol, &At[t * 8]);
        async_copy16(A + (size_t)(i0 + 64 + srow) * lda + k0 + scol, &At[2048 + t * 8]);
        async_copy16(B + (size_t)(j0 + srow) * ldb + k0 + scol, &Bt[t * 8]);
        async_copy16(B + (size_t)(j0 + 64 + srow) * ldb + k0 + scol, &Bt[2048 + t * 8]);
        __syncthreads();
        bf16x8 af[4], bg[4];
#pragma unroll
        for (int mi = 0; mi < 4; ++mi)
            af[mi] = *(const bf16x8*)&At[(wr * 64 + mi * 16 + fr) * 32 + fk];
#pragma unroll
        for (int ni = 0; ni < 4; ++ni)
            bg[ni] = *(const bf16x8*)&Bt[(wc * 64 + ni * 16 + fr) * 32 + fk];
#pragma unroll
        for (int mi = 0; mi < 4; ++mi)
#pragma unroll
            for (int ni = 0; ni < 4; ++ni)
                acc[mi][ni] = __builtin_amdgcn_mfma_f32_16x16x32_bf16(
                    af[mi], bg[ni], acc[mi][ni], 0, 0, 0);
    }
}

// P2 = 2*S@S - I  (and P2T)
__global__ __launch_bounds__(256) void k_poly2(const bf16* __restrict__ Sb,
                                               const bf16* __restrict__ SbT,
                                               bf16* __restrict__ P2,
                                               bf16* __restrict__ P2T) {
    __shared__ bf16 At[4096] __attribute__((aligned(16)));
    __shared__ bf16 Bt[4096] __attribute__((aligned(16)));
    const int i0 = blockIdx.y * 128, j0 = blockIdx.x * 128;
    f32x4 acc[4][4];
#pragma unroll
    for (int mi = 0; mi < 4; ++mi)
#pragma unroll
        for (int ni = 0; ni < 4; ++ni) acc[mi][ni] = f32x4{0.f, 0.f, 0.f, 0.f};
    mfma_tile_loop(Sb, SbT, NN, NN, NN, i0, j0, At, Bt, acc);
    const int t = threadIdx.x, lane = t & 63, w = t >> 6;
    const int wr = w >> 1, wc = w & 1;
    const int fr = lane & 15, rb = (lane >> 4) * 4;
#pragma unroll
    for (int mi = 0; mi < 4; ++mi)
#pragma unroll
        for (int ni = 0; ni < 4; ++ni) {
            const int ii = i0 + wr * 64 + mi * 16 + rb;
            const int jj = j0 + wc * 64 + ni * 16 + fr;
#pragma unroll
            for (int tt = 0; tt < 4; ++tt) {
                float v = 2.f * acc[mi][ni][tt] - ((ii + tt) == jj ? 1.f : 0.f);
                bf16 bv = (bf16)v;
                P2[(size_t)(ii + tt) * NN + jj] = bv;
                P2T[(size_t)jj * NN + (ii + tt)] = bv;
            }
        }
}

// P3 = 2*S@P2 - S
__global__ __launch_bounds__(256) void k_poly3(const bf16* __restrict__ Sb,
                                               const bf16* __restrict__ P2T,
                                               bf16* __restrict__ P3) {
    __shared__ bf16 At[4096] __attribute__((aligned(16)));
    __shared__ bf16 Bt[4096] __attribute__((aligned(16)));
    const int i0 = blockIdx.y * 128, j0 = blockIdx.x * 128;
    f32x4 acc[4][4];
#pragma unroll
    for (int mi = 0; mi < 4; ++mi)
#pragma unroll
        for (int ni = 0; ni < 4; ++ni) acc[mi][ni] = f32x4{0.f, 0.f, 0.f, 0.f};
    mfma_tile_loop(Sb, P2T, NN, NN, NN, i0, j0, At, Bt, acc);
    const int t = threadIdx.x, lane = t & 63, w = t >> 6;
    const int wr = w >> 1, wc = w & 1;
    const int fr = lane & 15, rb = (lane >> 4) * 4;
#pragma unroll
    for (int mi = 0; mi < 4; ++mi)
#pragma unroll
        for (int ni = 0; ni < 4; ++ni) {
            const int ii = i0 + wr * 64 + mi * 16 + rb;
            const int jj = j0 + wc * 64 + ni * 16 + fr;
#pragma unroll
            for (int tt = 0; tt < 4; ++tt) {
                float v = 2.f * acc[mi][ni][tt] - (float)Sb[(size_t)(ii + tt) * NN + jj];
                P3[(size_t)(ii + tt) * NN + jj] = (bf16)v;
            }
        }
}

// ---------------------------------------------------------------------------
// Big-GEMM template: BM=128, BN=384, BK=32, 8 waves (2M x 4N), acc[4][6],
// 3-deep circular LDS pipeline, ONE counted vmcnt + ONE barrier per K-tile.
// C[i][j] = sum_k A[i0+i][k]*B[j0+j][k]  (bt-form, both K-contiguous).
// EPI=0: out f32 [i][768] + bias (final GEMM).
// EPI=1: scatter bf16 into Xr4 interleaved layout (apply GEMM):
//        C[c=b*768+d][mn] -> Xr4[(b*512+n)*3072 + (m+1)*768 + d].
// Swizzle: LDS linear dest; source granule sg = (t&3)^((t>>2)&3)^((t>>4)&3);
// read slot = g^(fr&3)^((fr>>2)&3)  (involution pair, verified rounds 3-5).
// ---------------------------------------------------------------------------
template <int NT, int LDA, int LDB, int NWG, int NJ, int EPI>
__global__ __launch_bounds__(512) void k_mm(const bf16* __restrict__ A,
                                            const bf16* __restrict__ B,
                                            const float* __restrict__ bias,
                                            float* __restrict__ outF,
                                            bf16* __restrict__ outS) {
    __shared__ bf16 lds[3 * 4096 + 3 * 12288] __attribute__((aligned(16)));  // 96 KiB
    bf16* ldsA = lds;              // 3 bufs x [128][32]
    bf16* ldsB = lds + 3 * 4096;   // 3 bufs x [384][32]
    const int t = threadIdx.x;
    const int lane = t & 63;
    const int w = t >> 6;   // 0..7
    const int wr = w >> 2;  // 0..1 (M half: 64 rows)
    const int wc = w & 3;   // 0..3 (N quarter: 96 cols)
    const int wg = blockIdx.x;
    const int swz = (wg & 7) * (NWG / 8) + (wg >> 3);  // bijective XCD swizzle
    const int itile = swz / NJ;
    const int jtile = swz % NJ;
    const int i0 = itile * 128;
    const int j0 = jtile * 384;
    const int fr = lane & 15;
    const int g = lane >> 4;
    const int rslot8 = (g ^ (fr & 3) ^ ((fr >> 2) & 3)) * 8;
    const int abase = (wr * 64 + fr) * 32 + rslot8;
    const int bbase = (wc * 96 + fr) * 32 + rslot8;
    const int srow = t >> 2;
    const int sg8 = ((t & 3) ^ ((t >> 2) & 3) ^ ((t >> 4) & 3)) * 8;

    f32x4 acc[4][6];
#pragma unroll
    for (int mi = 0; mi < 4; ++mi)
#pragma unroll
        for (int ni = 0; ni < 6; ++ni) acc[mi][ni] = f32x4{0.f, 0.f, 0.f, 0.f};

    auto stage = [&](int kt) {
        const int buf = kt % 3;
        async_copy16(A + (size_t)(i0 + srow) * LDA + kt * 32 + sg8,
                     ldsA + buf * 4096 + t * 8);
        const bf16* bs = B + (size_t)(j0 + srow) * LDB + kt * 32 + sg8;
#pragma unroll
        for (int q = 0; q < 3; ++q)
            async_copy16(bs + (size_t)(128 * q) * LDB,
                         ldsB + buf * 12288 + q * 4096 + t * 8);
    };

    // Prologue: tiles 0 and 1 in flight; wait tile 0 (4 loads/tile/thread).
    stage(0);
    stage(1);
    asm volatile("s_waitcnt vmcnt(4)" ::: "memory");
    __builtin_amdgcn_s_barrier();
    __builtin_amdgcn_sched_barrier(0);

    for (int kt = 0; kt < NT; ++kt) {
        const int buf = kt % 3;
        if (kt + 2 < NT) stage(kt + 2);  // depth-2 prefetch (~2 K-tiles of cover)
        const bf16* As = ldsA + buf * 4096;
        const bf16* Bs = ldsB + buf * 12288;
        bf16x8 af[4], bg[6];
#pragma unroll
        for (int mi = 0; mi < 4; ++mi) af[mi] = *(const bf16x8*)&As[abase + mi * 512];
#pragma unroll
        for (int ni = 0; ni < 6; ++ni) bg[ni] = *(const bf16x8*)&Bs[bbase + ni * 512];
        __builtin_amdgcn_s_setprio(1);
#pragma unroll
        for (int mi = 0; mi < 4; ++mi)
#pragma unroll
            for (int ni = 0; ni < 6; ++ni)
                acc[mi][ni] = __builtin_amdgcn_mfma_f32_16x16x32_bf16(
                    af[mi], bg[ni], acc[mi][ni], 0, 0, 0);
        __builtin_amdgcn_s_setprio(0);
        // Boundary: tile kt+1 must be complete; tile kt+2's 4 loads stay in flight.
        if (kt + 2 < NT) {
            asm volatile("s_waitcnt vmcnt(4)" ::: "memory");
        } else {
            asm volatile("s_waitcnt vmcnt(0)" ::: "memory");
        }
        __builtin_amdgcn_s_barrier();
        __builtin_amdgcn_sched_barrier(0);
    }

    const int rb = g * 4;
    if constexpr (EPI == 0) {
        // Final GEMM epilogue: f32 out + bias, coalesced along jj.
#pragma unroll
        for (int ni = 0; ni < 6; ++ni) {
            const int jj = j0 + wc * 96 + ni * 16 + fr;
            const float bv = bias[jj];
#pragma unroll
            for (int mi = 0; mi < 4; ++mi) {
                const int ii = i0 + wr * 64 + mi * 16 + rb;
#pragma unroll
                for (int tt = 0; tt < 4; ++tt)
                    outF[(size_t)(ii + tt) * DD + jj] = acc[mi][ni][tt] + bv;
            }
        }
    } else {
        // Apply epilogue: LDS-transpose then coalesced bf16x8 scatter to Xr4.
        const int bblk = itile / 6;
        const int d0 = (itile % 6) * 128;
        bf16* epi = lds;  // [64][136] bf16 = 17.4 KiB, reuses pipeline LDS
#pragma unroll
        for (int ni = 0; ni < 6; ++ni) {
            __builtin_amdgcn_s_barrier();
#pragma unroll
            for (int mi = 0; mi < 4; ++mi) {
                bf16x4 p;
#pragma unroll
                for (int tt = 0; tt < 4; ++tt) p[tt] = (bf16)acc[mi][ni][tt];
                *(bf16x4*)&epi[(wc * 16 + fr) * 136 + wr * 64 + mi * 16 + rb] = p;
            }
            __builtin_amdgcn_s_barrier();
            const int row_e = t >> 3;          // 64 mn rows
            const int cpos = (t & 7) * 16;     // 128 c cols in 8 chunks
            const int mnl = (row_e >> 4) * 96 + ni * 16 + (row_e & 15);
            const int mn = jtile * 384 + mnl;
            const int m = mn >> 9;             // 16-chunks never cross m boundary
            const int n = mn & 511;
            bf16* dst = outS + ((size_t)(bblk * 512 + n)) * KK + (m + 1) * DD + d0 + cpos;
            *(bf16x8*)dst = *(const bf16x8*)&epi[row_e * 136 + cpos];
            *(bf16x8*)(dst + 8) = *(const bf16x8*)&epi[row_e * 136 + cpos + 8];
        }
    }
}

// ---------------------------------------------------------------------------
// Launch
// ---------------------------------------------------------------------------
extern "C" void kernel_launch(void* const* d_in, const int* in_sizes, int n_in,
                              void* d_out, int out_size, void* d_ws, size_t ws_size,
                              hipStream_t stream) {
    const float* inputs = (const float*)d_in[0];   // [32,512,768]
    const float* adj = (const float*)d_in[1];      // [512,512]
    const float* weights = (const float*)d_in[2];  // [3072,768]
    const float* biases = (const float*)d_in[3];   // [768]
    float* out = (float*)d_out;                    // [32,512,768]

    char* ws = (char*)d_ws;
    const size_t SQ = (size_t)NN * NN * 2;  // 512 KiB per P matrix
    float* dv = (float*)(ws + 0);
    // Pcat = [P1(=Sb); P2; P3] CONTIGUOUS (B operand of the apply GEMM).
    bf16* Pcat = (bf16*)(ws + 4096);                     // 1.5 MiB
    bf16* SbT = (bf16*)(ws + 4096 + 3 * SQ);             // 512 KiB
    bf16* P2T = (bf16*)(ws + 4096 + 4 * SQ);             // 512 KiB
    bf16* WtK = (bf16*)(ws + 4096 + 5 * SQ);             // 768*3072*2 = 4.5 MiB
    char* p = ws + 4096 + 5 * SQ + (size_t)DD * KK * 2;
    bf16* XT0 = (bf16*)p;                                // [32][768][512] = 24 MiB
    bf16* Xr4 = (bf16*)(p + (size_t)BB * NN * DD * 2);   // [16384][3072] = 96 MiB
    // total ~127.5 MiB

    bf16* Sb = Pcat;
    bf16* P2 = Pcat + (size_t)NN * NN;
    bf16* P3 = Pcat + (size_t)2 * NN * NN;

    k_rowsum<<<NN, 64, 0, stream>>>(adj, dv);
    k_support2<<<dim3(16, 16), dim3(32, 8), 0, stream>>>(adj, dv, Sb, SbT);
    k_prepwt2<<<dim3(24, 24, 4), dim3(32, 8), 0, stream>>>(weights, WtK);
    k_prepx<<<dim3(DD / 64, NN / 64, BB), 256, 0, stream>>>(inputs, Xr4, XT0);

    k_poly2<<<dim3(4, 4), 256, 0, stream>>>(Sb, SbT, P2, P2T);
    k_poly3<<<dim3(4, 4), 256, 0, stream>>>(Sb, P2T, P3);

    // Apply GEMM: C[c=b*768+d][mn] = XT0flat @ Pcat^T; scatter to Xr4 slabs 1-3.
    // M=24576 (192 i-tiles), N=1536 (4 j-tiles), K=512 (16 K-tiles), 768 blocks.
    k_mm<16, 512, 512, 768, 4, 1><<<768, 512, 0, stream>>>(
        XT0, Pcat, nullptr, nullptr, Xr4);

    // Final GEMM: out = Xr4 @ WtK^T + bias.
    // M=16384 (128 i-tiles), N=768 (2 j-tiles), K=3072 (96 K-tiles), 256 blocks.
    k_mm<96, KK, KK, 256, 2, 0><<<256, 512, 0, stream>>>(
        Xr4, WtK, biases, out, nullptr);
}